// Round 1
// baseline (113.107 us; speedup 1.0000x reference)
//
#include <hip/hip_runtime.h>
#include <stdint.h>

#define TT 192
#define DIMM 512
#define NHEADS 8
#define DHEAD 64

typedef float f32x4 __attribute__((ext_vector_type(4)));
typedef short s16x8 __attribute__((ext_vector_type(8)));

__device__ __forceinline__ float bf2f(uint16_t b) {
    union { uint32_t u; float f; } v; v.u = ((uint32_t)b) << 16; return v.f;
}
__device__ __forceinline__ uint16_t f2bf(float f) {
    union { float f; uint32_t u; } v; v.f = f;
    uint32_t u = v.u;
    uint32_t r = (u + 0x7FFFu + ((u >> 16) & 1u)) >> 16;   // RTN-even
    return (uint16_t)r;
}

// ---------------- LayerNorm: x fp32 [384][512] -> xn bf16 ----------------
__global__ __launch_bounds__(256) void k_ln(const float* __restrict__ x,
                                            const float* __restrict__ gamma,
                                            const float* __restrict__ beta,
                                            uint16_t* __restrict__ xn) {
    int row = blockIdx.x;
    int tid = threadIdx.x;
    const float* xr = x + row * DIMM;
    float2 v = *(const float2*)(xr + tid * 2);
    float s = v.x + v.y;
    float s2 = v.x * v.x + v.y * v.y;
    for (int off = 32; off; off >>= 1) {
        s  += __shfl_down(s, off);
        s2 += __shfl_down(s2, off);
    }
    __shared__ float ws1[4], ws2[4];
    int w = tid >> 6, lane = tid & 63;
    if (lane == 0) { ws1[w] = s; ws2[w] = s2; }
    __syncthreads();
    if (tid == 0) {
        float a = 0.f, b = 0.f;
        for (int i = 0; i < 4; i++) { a += ws1[i]; b += ws2[i]; }
        ws1[0] = a; ws2[0] = b;
    }
    __syncthreads();
    float mu = ws1[0] * (1.f / DIMM);
    float var = ws2[0] * (1.f / DIMM) - mu * mu;
    float rs = rsqrtf(var + 1e-5f);
    float o0 = (v.x - mu) * rs * gamma[tid * 2]     + beta[tid * 2];
    float o1 = (v.y - mu) * rs * gamma[tid * 2 + 1] + beta[tid * 2 + 1];
    uint32_t pk = (uint32_t)f2bf(o0) | ((uint32_t)f2bf(o1) << 16);
    *(uint32_t*)(xn + row * DIMM + tid * 2) = pk;
}

// ---------- proj GEMM: xn[384][512]bf16 @ W[2560][512]f32^T + bias ----------
// epilogue scatters into comp[5][2][8][192][64] bf16
__global__ __launch_bounds__(256) void k_gemm_proj(const uint16_t* __restrict__ A,
                                                   const float* __restrict__ B,
                                                   const float* __restrict__ bias,
                                                   uint16_t* __restrict__ comp) {
    __shared__ uint16_t Asm[64][40];
    __shared__ uint16_t Bsm[64][40];
    int n0 = blockIdx.x * 64, m0 = blockIdx.y * 64;
    int tid = threadIdx.x;
    int lr = tid >> 2, seg = tid & 3;
    int w = tid >> 6, lane = tid & 63, g = lane >> 4, c = lane & 15;
    f32x4 acc[4] = {};
    for (int k0 = 0; k0 < 512; k0 += 32) {
        *(s16x8*)(&Asm[lr][seg * 8]) = *(const s16x8*)(A + (m0 + lr) * 512 + k0 + seg * 8);
        float4 b0 = *(const float4*)(B + (n0 + lr) * 512 + k0 + seg * 8);
        float4 b1 = *(const float4*)(B + (n0 + lr) * 512 + k0 + seg * 8 + 4);
        s16x8 bq;
        bq[0] = (short)f2bf(b0.x); bq[1] = (short)f2bf(b0.y);
        bq[2] = (short)f2bf(b0.z); bq[3] = (short)f2bf(b0.w);
        bq[4] = (short)f2bf(b1.x); bq[5] = (short)f2bf(b1.y);
        bq[6] = (short)f2bf(b1.z); bq[7] = (short)f2bf(b1.w);
        *(s16x8*)(&Bsm[lr][seg * 8]) = bq;
        __syncthreads();
        s16x8 af = *(const s16x8*)(&Asm[w * 16 + c][g * 8]);
#pragma unroll
        for (int nt = 0; nt < 4; nt++) {
            s16x8 bf = *(const s16x8*)(&Bsm[nt * 16 + c][g * 8]);
            acc[nt] = __builtin_amdgcn_mfma_f32_16x16x32_bf16(af, bf, acc[nt], 0, 0, 0);
        }
        __syncthreads();
    }
    // epilogue: n -> (cmp, h, dh); m -> (bb, t)
    int cmp = n0 / 512;
    int h   = (n0 % 512) / 64;
    int bb  = m0 / 192;
    int t0  = m0 % 192;
    uint16_t* base = comp + (((size_t)(cmp * 2 + bb) * 8 + h) * TT) * 64;
#pragma unroll
    for (int nt = 0; nt < 4; nt++) {
        int dh = nt * 16 + c;
        float bv = bias[n0 + nt * 16 + c];
#pragma unroll
        for (int r = 0; r < 4; r++) {
            int t = t0 + w * 16 + g * 4 + r;
            base[t * 64 + dh] = f2bf(acc[nt][r] + bv);
        }
    }
}

// ---------------- fused trittention ----------------
// grid (12 qtiles, 8 heads, 2 batch), 256 threads (4 waves)
__global__ __launch_bounds__(256) void k_tritt(const uint16_t* __restrict__ comp,
                                               uint16_t* __restrict__ Zbuf) {
    __shared__ uint16_t DT[64][200];
    __shared__ uint16_t ET[64][200];
    __shared__ float Pbuf[16][196];
    __shared__ float zpart[16][16];
    __shared__ float Zrec[16];

    int qt = blockIdx.x, h = blockIdx.y, bb = blockIdx.z;
    int q0 = qt * 16;
    const size_t hs = (size_t)TT * 64;
    const uint16_t* Ac = comp + ((size_t)(0 * 2 + bb) * 8 + h) * hs;
    const uint16_t* Bc = comp + ((size_t)(1 * 2 + bb) * 8 + h) * hs;
    const uint16_t* Cc = comp + ((size_t)(2 * 2 + bb) * 8 + h) * hs;
    const uint16_t* Dc = comp + ((size_t)(3 * 2 + bb) * 8 + h) * hs;
    const uint16_t* Ec = comp + ((size_t)(4 * 2 + bb) * 8 + h) * hs;

    int tid = threadIdx.x, w = tid >> 6, lane = tid & 63, g = lane >> 4, c = lane & 15;

    for (int i = tid; i < 16 * 196; i += 256) ((float*)Pbuf)[i] = 0.f;
    for (int i = tid; i < TT * 64; i += 256) {
        int r = i >> 6, d = i & 63;
        DT[d][r] = Dc[i];
        ET[d][r] = Ec[i];
    }
    // B-comp fragments in registers: wave w covers r in [w*48, w*48+48)
    s16x8 bfr[3][2];
#pragma unroll
    for (int rt = 0; rt < 3; rt++)
#pragma unroll
        for (int ks = 0; ks < 2; ks++)
            bfr[rt][ks] = *(const s16x8*)(Bc + (w * 48 + rt * 16 + c) * 64 + ks * 32 + g * 8);
    // c query registers (pre-scaled by 1/64)
    float cre[16];
#pragma unroll
    for (int ks = 0; ks < 2; ks++) {
        s16x8 cv = *(const s16x8*)(Cc + (q0 + c) * 64 + ks * 32 + g * 8);
#pragma unroll
        for (int j = 0; j < 8; j++)
            cre[ks * 8 + j] = bf2f((uint16_t)cv[j]) * (1.f / 64.f);
    }
    __syncthreads();

    float pracc[3][4] = {};
    s16x8 an0 = *(const s16x8*)(Ac + g * 8);
    s16x8 an1 = *(const s16x8*)(Ac + 32 + g * 8);
    for (int l = 0; l < TT; l++) {
        s16x8 a0 = an0, a1 = an1;
        if (l + 1 < TT) {
            an0 = *(const s16x8*)(Ac + (l + 1) * 64 + g * 8);
            an1 = *(const s16x8*)(Ac + (l + 1) * 64 + 32 + g * 8);
        }
        s16x8 gf0, gf1;
#pragma unroll
        for (int j = 0; j < 8; j++) {
            gf0[j] = (short)f2bf(cre[j]     * bf2f((uint16_t)a0[j]));
            gf1[j] = (short)f2bf(cre[8 + j] * bf2f((uint16_t)a1[j]));
        }
        float psum = 0.f;
#pragma unroll
        for (int rt = 0; rt < 3; rt++) {
            f32x4 s = {};
            s = __builtin_amdgcn_mfma_f32_16x16x32_bf16(bfr[rt][0], gf0, s, 0, 0, 0);
            s = __builtin_amdgcn_mfma_f32_16x16x32_bf16(bfr[rt][1], gf1, s, 0, 0, 0);
#pragma unroll
            for (int r = 0; r < 4; r++) {
                float p = __expf(s[r]);
                pracc[rt][r] += p;
                psum += p;
            }
        }
        psum += __shfl_xor(psum, 16);
        psum += __shfl_xor(psum, 32);
        if (g == 0) atomicAdd(&Pbuf[c][l], psum);
    }
    __syncthreads();
    // denominators Z[q] = sum_l Pl[q][l]
    {
        int q = tid >> 4, j = tid & 15;
        float sd = 0.f;
        for (int i = j; i < TT; i += 16) sd += Pbuf[q][i];
        zpart[q][j] = sd;
    }
    __syncthreads();
    if (tid < 16) {
        float sdd = 0.f;
        for (int j2 = 0; j2 < 16; j2++) sdd += zpart[tid][j2];
        Zrec[tid] = 1.f / sdd;
    }
    __syncthreads();
    // GEMM1: z1 = Pl @ Dcomp   (wave w owns d-tile w)
    f32x4 zacc = {};
#pragma unroll
    for (int ks = 0; ks < 6; ks++) {
        s16x8 afr;
#pragma unroll
        for (int j = 0; j < 8; j++) afr[j] = (short)f2bf(Pbuf[c][ks * 32 + g * 8 + j]);
        s16x8 bfd = *(const s16x8*)(&DT[w * 16 + c][ks * 32 + g * 8]);
        zacc = __builtin_amdgcn_mfma_f32_16x16x32_bf16(afr, bfd, zacc, 0, 0, 0);
    }
    __syncthreads();
    // overwrite Pbuf with Pr from registers
#pragma unroll
    for (int rt = 0; rt < 3; rt++)
#pragma unroll
        for (int r = 0; r < 4; r++)
            Pbuf[c][w * 48 + rt * 16 + g * 4 + r] = pracc[rt][r];
    __syncthreads();
    // GEMM2: z2 = Pr @ Ecomp (accumulate)
#pragma unroll
    for (int ks = 0; ks < 6; ks++) {
        s16x8 afr;
#pragma unroll
        for (int j = 0; j < 8; j++) afr[j] = (short)f2bf(Pbuf[c][ks * 32 + g * 8 + j]);
        s16x8 bfe = *(const s16x8*)(&ET[w * 16 + c][ks * 32 + g * 8]);
        zacc = __builtin_amdgcn_mfma_f32_16x16x32_bf16(afr, bfe, zacc, 0, 0, 0);
    }
    // epilogue: Zbuf[bb*192 + q0 + q][h*64 + w*16 + c]
#pragma unroll
    for (int r = 0; r < 4; r++) {
        int q = g * 4 + r;
        float val = zacc[r] * Zrec[q];
        Zbuf[((size_t)(bb * TT + q0 + q)) * 512 + h * 64 + w * 16 + c] = f2bf(val);
    }
}

// ---------- out GEMM: Zbuf[384][512]bf16 @ W_out[512][512]f32^T + bias -> fp32 ----------
__global__ __launch_bounds__(256) void k_gemm_out(const uint16_t* __restrict__ A,
                                                  const float* __restrict__ B,
                                                  const float* __restrict__ bias,
                                                  float* __restrict__ out) {
    __shared__ uint16_t Asm[64][40];
    __shared__ uint16_t Bsm[64][40];
    int n0 = blockIdx.x * 64, m0 = blockIdx.y * 64;
    int tid = threadIdx.x;
    int lr = tid >> 2, seg = tid & 3;
    int w = tid >> 6, lane = tid & 63, g = lane >> 4, c = lane & 15;
    f32x4 acc[4] = {};
    for (int k0 = 0; k0 < 512; k0 += 32) {
        *(s16x8*)(&Asm[lr][seg * 8]) = *(const s16x8*)(A + (m0 + lr) * 512 + k0 + seg * 8);
        float4 b0 = *(const float4*)(B + (n0 + lr) * 512 + k0 + seg * 8);
        float4 b1 = *(const float4*)(B + (n0 + lr) * 512 + k0 + seg * 8 + 4);
        s16x8 bq;
        bq[0] = (short)f2bf(b0.x); bq[1] = (short)f2bf(b0.y);
        bq[2] = (short)f2bf(b0.z); bq[3] = (short)f2bf(b0.w);
        bq[4] = (short)f2bf(b1.x); bq[5] = (short)f2bf(b1.y);
        bq[6] = (short)f2bf(b1.z); bq[7] = (short)f2bf(b1.w);
        *(s16x8*)(&Bsm[lr][seg * 8]) = bq;
        __syncthreads();
        s16x8 af = *(const s16x8*)(&Asm[w * 16 + c][g * 8]);
#pragma unroll
        for (int nt = 0; nt < 4; nt++) {
            s16x8 bf = *(const s16x8*)(&Bsm[nt * 16 + c][g * 8]);
            acc[nt] = __builtin_amdgcn_mfma_f32_16x16x32_bf16(af, bf, acc[nt], 0, 0, 0);
        }
        __syncthreads();
    }
#pragma unroll
    for (int nt = 0; nt < 4; nt++) {
        int n = n0 + nt * 16 + c;
        float bv = bias[n];
#pragma unroll
        for (int r = 0; r < 4; r++) {
            int m = m0 + w * 16 + g * 4 + r;
            out[(size_t)m * 512 + n] = acc[nt][r] + bv;
        }
    }
}

extern "C" void kernel_launch(void* const* d_in, const int* in_sizes, int n_in,
                              void* d_out, int out_size, void* d_ws, size_t ws_size,
                              hipStream_t stream) {
    const float* x     = (const float*)d_in[0];
    const float* gamma = (const float*)d_in[1];
    const float* beta  = (const float*)d_in[2];
    const float* Wab   = (const float*)d_in[3];
    const float* bab   = (const float*)d_in[4];
    const float* Wout  = (const float*)d_in[5];
    const float* bout  = (const float*)d_in[6];
    float* out = (float*)d_out;

    char* ws = (char*)d_ws;
    uint16_t* xn   = (uint16_t*)ws;                     // 384*512*2     = 393216
    uint16_t* comp = (uint16_t*)(ws + 393216);          // 5*2*8*192*64*2= 1966080
    uint16_t* Zbuf = (uint16_t*)(ws + 393216 + 1966080);// 384*512*2     = 393216

    k_ln<<<384, 256, 0, stream>>>(x, gamma, beta, xn);
    k_gemm_proj<<<dim3(40, 6), 256, 0, stream>>>(xn, Wab, bab, comp);
    k_tritt<<<dim3(12, 8, 2), 256, 0, stream>>>(comp, Zbuf);
    k_gemm_out<<<dim3(8, 6), 256, 0, stream>>>(Zbuf, Wout, bout, out);
}